// Round 16
// baseline (445.573 us; speedup 1.0000x reference)
//
#include <hip/hip_runtime.h>
#include <stdint.h>

// W8A16 quantized linear — ZERO-LDS, ZERO-BARRIER dataflow GEMM.
//   Pre-pass: BOTH operands rewritten fragment-tiled:
//     Af2: for (m16 = row/16, kt = k/32): 64 lanes' 16B chunks contiguous
//          (lane l = qk*16+fr holds A[m16*16+fr][kt*32+qk*8..+8]).
//     Wf2: same for W = fp16(q*scale) (layout HW-verified in R15).
//   GEMM: 256x256 logical tile, 8 independent waves (2M x 4N), wave tile
//     128x64, acc[8][4] AGPR. All frags load global->VGPR via coalesced
//     1KB/inst reads; double-buffered by name; per-wave compiler-counted
//     vmcnt; NO LDS, NO barriers.
// Why: R5-R15 (seven schedule variants) all measured = serial sum of
//   MFMA + per-tile memory service — barrier lockstep at 1 block/CU adds
//   every pipe's time. m114: INDEPENDENT waves overlap MFMA & memory
//   fully. Removing the barriers buys the overlap that intra-wave
//   scheduling never did. MFMA floor 1242 cyc/tile; TA ~1000 cyc rides
//   under other waves' MFMA.
// Regs: 128 AGPR acc + ~111 arch (af 64, bf 32, addr) <= 256 unified.

#define M_DIM 8192
#define N_DIM 4096
#define K_DIM 4096
#define BM 256
#define BN 256
#define BK 32
#define NKT (K_DIM / BK)   // 128 K-tiles

typedef _Float16 f16;
typedef f16 f16x8 __attribute__((ext_vector_type(8)));
typedef f16 f16x2 __attribute__((ext_vector_type(2)));
typedef float f32x4 __attribute__((ext_vector_type(4)));

static __device__ __forceinline__ f16x2 cvt2(float a, float b) {
  return __builtin_bit_cast(f16x2, __builtin_amdgcn_cvt_pkrtz(a, b));
}

// ---------------- pre-pass kernels ----------------

// A (f32 row-major) -> fragment-tiled f16 Af2.
// Block = m16 (0..511), thread t: l=t&63 (fr=l&15, qk=l>>4), g=t>>6.
// Row o = m16*16+fr; elem write idx ((m16*128+kt)*64+l)*8 (16B/lane, coalesced).
__global__ __launch_bounds__(256) void conv_a2_kernel(
    const float* __restrict__ A, f16* __restrict__ Af2)
{
  const int m16 = blockIdx.x;
  const int t  = threadIdx.x;
  const int l  = t & 63;
  const int g  = t >> 6;          // 0..3
  const int fr = l & 15;
  const int qk = l >> 4;
  const int o  = m16 * 16 + fr;
  const float* arow = A + (size_t)o * K_DIM + qk * 8;
  f16* wbase = Af2 + (size_t)m16 * 128 * 64 * 8 + (size_t)l * 8;
  for (int kt = g; kt < NKT; kt += 4) {
    const float* p = arow + kt * 32;
    f32x4 v0 = *(const f32x4*)(p);
    f32x4 v1 = *(const f32x4*)(p + 4);
    f16x2 a = cvt2(v0.x, v0.y), b = cvt2(v0.z, v0.w);
    f16x2 c = cvt2(v1.x, v1.y), d = cvt2(v1.z, v1.w);
    *(f16x8*)(wbase + (size_t)kt * 512) =
        (f16x8){a.x, a.y, b.x, b.y, c.x, c.y, d.x, d.y};
  }
}

// W -> fragment-tiled Wf2 (R15, HW-verified correct).
__global__ __launch_bounds__(256) void conv_b2_kernel(
    const int* __restrict__ Qw, const float* __restrict__ Sc,
    f16* __restrict__ Wf2)
{
  const int c16 = blockIdx.x;
  const int t  = threadIdx.x;
  const int l  = t & 63;
  const int g  = t >> 6;
  const int fr = l & 15;
  const int qk = l >> 4;
  const int o  = c16 * 16 + fr;
  const float s = Sc[o];
  const int* qrow = Qw + (size_t)o * K_DIM + qk * 8;
  f16* wbase = Wf2 + (size_t)c16 * 128 * 64 * 8 + (size_t)l * 8;
  for (int kt = g; kt < NKT; kt += 4) {
    const int* q = qrow + kt * 32;
    int4 u0 = *(const int4*)(q);
    int4 u1 = *(const int4*)(q + 4);
    f16x2 a = cvt2((float)u0.x * s, (float)u0.y * s);
    f16x2 b = cvt2((float)u0.z * s, (float)u0.w * s);
    f16x2 c = cvt2((float)u1.x * s, (float)u1.y * s);
    f16x2 d = cvt2((float)u1.z * s, (float)u1.w * s);
    *(f16x8*)(wbase + (size_t)kt * 512) =
        (f16x8){a.x, a.y, b.x, b.y, c.x, c.y, d.x, d.y};
  }
}

// ---------------- main GEMM (no LDS, no barriers) ----------------

// coalesced fragment loads: A frag mi at +mi*262144B, B frag ni at
// +ni*524288B, K-tile at +kt*1024B, lane at +lane*16B (folded in base).
#define LOAD_A(dst, ktn) do { \
  dst[0] = *(const f16x8*)(abase + 0 * 262144 + (size_t)(ktn) * 1024); \
  dst[1] = *(const f16x8*)(abase + 1 * 262144 + (size_t)(ktn) * 1024); \
  dst[2] = *(const f16x8*)(abase + 2 * 262144 + (size_t)(ktn) * 1024); \
  dst[3] = *(const f16x8*)(abase + 3 * 262144 + (size_t)(ktn) * 1024); \
  dst[4] = *(const f16x8*)(abase + 4 * 262144 + (size_t)(ktn) * 1024); \
  dst[5] = *(const f16x8*)(abase + 5 * 262144 + (size_t)(ktn) * 1024); \
  dst[6] = *(const f16x8*)(abase + 6 * 262144 + (size_t)(ktn) * 1024); \
  dst[7] = *(const f16x8*)(abase + 7 * 262144 + (size_t)(ktn) * 1024); \
  } while (0)

#define LOAD_B(dst, ktn) do { \
  dst[0] = *(const f16x8*)(bbase + 0 * 524288 + (size_t)(ktn) * 1024); \
  dst[1] = *(const f16x8*)(bbase + 1 * 524288 + (size_t)(ktn) * 1024); \
  dst[2] = *(const f16x8*)(bbase + 2 * 524288 + (size_t)(ktn) * 1024); \
  dst[3] = *(const f16x8*)(bbase + 3 * 524288 + (size_t)(ktn) * 1024); \
  } while (0)

// One K-tile: prefetch NXT while computing CUR. Compiler inserts counted
// per-wave vmcnt before the first MFMA that uses CUR.
#define TILE(KT, AC, BC, AN, BN_, M1) do { \
  if (M1) { LOAD_A(AN, (KT) + 1); LOAD_B(BN_, (KT) + 1); } \
  _Pragma("unroll") \
  for (int _m = 0; _m < 8; ++_m) \
    _Pragma("unroll") \
    for (int _n = 0; _n < 4; ++_n) \
      acc[_m][_n] = __builtin_amdgcn_mfma_f32_16x16x32_f16( \
          AC[_m], BC[_n], acc[_m][_n], 0, 0, 0); \
  } while (0)

__global__ __launch_bounds__(512, 1) void w8a16_gemm_f16_kernel(
    const f16* __restrict__ Af2,  // fragment-tiled A
    const f16* __restrict__ Wf2,  // fragment-tiled W (scale folded)
    float* __restrict__ Out)      // [M][N]
{
  const int t    = threadIdx.x;
  const int lane = t & 63;
  const int wid  = t >> 6;       // 0..7
  const int wm   = wid >> 2;     // 0..1 (M interleave)
  const int wn   = wid & 3;      // 0..3 (N interleave)
  const int fr   = lane & 15;

  // XCD swizzle: 512 blocks; concurrent blocks on one XCD share tn
  const int bid = blockIdx.x;
  const int swz = (bid & 7) * 64 + (bid >> 3);
  const int tn  = swz >> 5;      // 16 N-tiles
  const int tm  = swz & 31;      // 32 M-tiles

  // frag bases: m16 = tm*16 + 2*mi + wm ; c16 = tn*16 + ni*4 + wn
  const char* abase = (const char*)Af2
      + ((size_t)(tm * 16 + wm) * 128) * 1024 + (size_t)lane * 16;
  const char* bbase = (const char*)Wf2
      + ((size_t)(tn * 16 + wn) * 128) * 1024 + (size_t)lane * 16;

  f32x4 acc[8][4] = {};
  f16x8 aA[8], aB[8], bA[4], bB[4];

  LOAD_A(aA, 0);
  LOAD_B(bA, 0);

  for (int kt = 0; kt < NKT - 2; kt += 2) {
    TILE(kt,     aA, bA, aB, bB, 1);
    TILE(kt + 1, aB, bB, aA, bA, 1);
  }
  TILE(NKT - 2, aA, bA, aB, bB, 1);
  TILE(NKT - 1, aB, bB, aA, bA, 0);

  // epilogue: C/D col = lane&15, row = (lane>>4)*4 + reg
  const int fq = lane >> 4;
  #pragma unroll
  for (int mi = 0; mi < 8; ++mi) {
    const size_t row = (size_t)tm * BM + (2 * mi + wm) * 16 + fq * 4;
    #pragma unroll
    for (int ni = 0; ni < 4; ++ni) {
      const size_t col = (size_t)tn * BN + ni * 64 + wn * 16 + fr;
      #pragma unroll
      for (int r = 0; r < 4; ++r)
        Out[(row + r) * N_DIM + col] = acc[mi][ni][r];
    }
  }
}

// ---------------- fallback (round-3 verified path) ----------------

__global__ __launch_bounds__(256) void w8a16_gemm_fb_kernel(
    const float* __restrict__ A, const int* __restrict__ Qw,
    const float* __restrict__ Sc, float* __restrict__ Out)
{
  __shared__ __align__(16) float Asf[2][128 * 32];
  __shared__ __align__(16) f16 Bsf[2][128][32];

  const int t = threadIdx.x, lane = t & 63, wid = t >> 6;
  const int wr = wid >> 1, wc = wid & 1;
  const int nwg = gridDim.x, cpx = nwg >> 3, bid = blockIdx.x;
  const int swz = (bid & 7) * cpx + (bid >> 3);
  const int tn = swz & 31, tm = swz >> 5;
  const size_t a_base = (size_t)tm * 128 * K_DIM;
  const size_t b_base = (size_t)tn * 128 * K_DIM;
  f32x4 acc[4][4] = {};
  const int a_r = t >> 3;
  const int a_slog = (t & 7) ^ ((t >> 3) & 7);

  auto stageA = [&](int buf, int kt) {
    #pragma unroll
    for (int c = 0; c < 4; ++c) {
      const float* g = A + a_base + (size_t)(c * 32 + a_r) * K_DIM + kt * 32 + a_slog * 4;
      char* l = (char*)&Asf[buf][0] + c * 4096 + wid * 1024;
      __builtin_amdgcn_global_load_lds(
          (const __attribute__((address_space(1))) void*)g,
          (__attribute__((address_space(3))) void*)l, 16, 0, 0);
    }
  };
  const int b_r = t >> 3, b_col = (t & 7) * 4;
  auto loadB = [&](int kt, int4* v) {
    #pragma unroll
    for (int c = 0; c < 4; ++c)
      v[c] = *(const int4*)(Qw + b_base + (size_t)(c * 32 + b_r) * K_DIM + kt * 32 + b_col);
  };
  auto writeB = [&](int buf, const int4* v) {
    #pragma unroll
    for (int c = 0; c < 4; ++c) {
      f16x2 lo = cvt2((float)v[c].x, (float)v[c].y);
      f16x2 hi = cvt2((float)v[c].z, (float)v[c].w);
      *(f16x2*)&Bsf[buf][c * 32 + b_r][b_col] = lo;
      *(f16x2*)&Bsf[buf][c * 32 + b_r][b_col + 2] = hi;
    }
  };
  auto compute = [&](int buf) {
    const int fr2 = lane & 15, q = lane >> 4;
    f16x8 af2[4], bf2[4];
    #pragma unroll
    for (int i = 0; i < 4; ++i) {
      const int r = wr * 64 + i * 16 + fr2;
      const float* base = &Asf[buf][0] + r * 32;
      const int s0 = q * 2;
      f32x4 a0 = *(const f32x4*)(base + ((s0 ^ (r & 7)) * 4));
      f32x4 a1 = *(const f32x4*)(base + (((s0 + 1) ^ (r & 7)) * 4));
      f16x2 p0 = cvt2(a0.x, a0.y), p1 = cvt2(a0.z, a0.w);
      f16x2 p2 = cvt2(a1.x, a1.y), p3 = cvt2(a1.z, a1.w);
      af2[i] = (f16x8){p0.x, p0.y, p1.x, p1.y, p2.x, p2.y, p3.x, p3.y};
      bf2[i] = *(const f16x8*)&Bsf[buf][wc * 64 + i * 16 + fr2][q * 8];
    }
    #pragma unroll
    for (int mi = 0; mi < 4; ++mi)
      #pragma unroll
      for (int ni = 0; ni < 4; ++ni)
        acc[mi][ni] = __builtin_amdgcn_mfma_f32_16x16x32_f16(
            af2[mi], bf2[ni], acc[mi][ni], 0, 0, 0);
  };

  { int4 b0[4]; stageA(0, 0); loadB(0, b0); writeB(0, b0); }
  __syncthreads();
  for (int kt = 0; kt < K_DIM / 32; ++kt) {
    const int buf = kt & 1;
    const bool more = (kt + 1) < K_DIM / 32;
    int4 nb[4];
    if (more) { stageA(buf ^ 1, kt + 1); loadB(kt + 1, nb); }
    compute(buf);
    if (more) writeB(buf ^ 1, nb);
    __syncthreads();
  }
  const int fr2 = lane & 15, fq = lane >> 4;
  const int cb = tn * 128 + wc * 64 + fr2;
  const int rb = tm * 128 + wr * 64 + fq * 4;
  #pragma unroll
  for (int ni = 0; ni < 4; ++ni) {
    const float s = Sc[cb + ni * 16];
    #pragma unroll
    for (int mi = 0; mi < 4; ++mi)
      #pragma unroll
      for (int r = 0; r < 4; ++r)
        Out[(size_t)(rb + mi * 16 + r) * N_DIM + (cb + ni * 16)] =
            acc[mi][ni][r] * s;
  }
}

extern "C" void kernel_launch(void* const* d_in, const int* in_sizes, int n_in,
                              void* d_out, int out_size, void* d_ws, size_t ws_size,
                              hipStream_t stream) {
  const float* A  = (const float*)d_in[0];
  const int*   Qw = (const int*)d_in[1];
  const float* Sc = (const float*)d_in[2];
  float*       Out = (float*)d_out;

  const size_t a_bytes = (size_t)M_DIM * K_DIM * sizeof(f16);  // 64 MB
  const size_t w_bytes = (size_t)N_DIM * K_DIM * sizeof(f16);  // 32 MB

  if (ws_size >= a_bytes + w_bytes) {
    f16* Af2 = (f16*)d_ws;
    f16* Wf2 = (f16*)((char*)d_ws + a_bytes);
    conv_a2_kernel<<<M_DIM / 16, 256, 0, stream>>>(A, Af2);
    conv_b2_kernel<<<N_DIM / 16, 256, 0, stream>>>(Qw, Sc, Wf2);
    dim3 grid((M_DIM / BM) * (N_DIM / BN));  // 32*16 = 512
    w8a16_gemm_f16_kernel<<<grid, 512, 0, stream>>>(Af2, Wf2, Out);
  } else {
    dim3 grid((M_DIM / 128) * (N_DIM / 128));
    w8a16_gemm_fb_kernel<<<grid, 256, 0, stream>>>(A, Qw, Sc, Out);
  }
}

// Round 17
// 299.934 us; speedup vs baseline: 1.4856x; 1.4856x over previous
//
#include <hip/hip_runtime.h>
#include <stdint.h>

// W8A16 quantized linear, two-phase:
//   Pre-pass: A f32->f16 (64 MB), W = fp16(q*scale) (32 MB) into d_ws.
//   GEMM: m201-faithful 8-phase schedule on R6's validated geometry:
//     256x256 tile, BK=64 K-steps, 2 K-steps/iter, 8 waves (2M x 4N),
//     wave tile 128x64 (acc[8][4] AGPR), LDS 128 KB (2buf x 2half x
//     128x64 x A,B), XOR-swizzled (0 conflicts, HW-verified R5/R6).
//   Per phase: {ds_reads for this phase's quadrant} + {ONE half-tile
//     stage} + [lgkm(8) if 12 reads] + barrier + lgkm(0) + setprio/16
//     MFMA/setprio + barrier. vmcnt(6) ONLY at phases 4 and 8.
// Stage map (compile-time): ph1: buf1.A1(kt+1); ph2: buf0.A0(kt+2);
//   ph3: buf0.B0(kt+2); ph4: buf0.B1(kt+2)+VMW(6); ph5: buf0.A1(kt+2);
//   ph6: buf1.A0(kt+3); ph7: buf1.B0(kt+3); ph8: buf1.B1(kt+3)+VMW(6).
// FIFO ledger (halves, 2 insts each): entering iter: [A0,B0,B1](kt+1).
//   ph4 VMW(6) keeps 3 newest = kt+2's A0,B0,B1 -> retires ALL kt+1
//   halves (read ph5-7, sealed by ph4 barrier). ph8 VMW(6) keeps
//   [A0,B0,B1](kt+3) -> retires kt+2 (read next ph1-3). Invariant holds.
//   Stage->confirm slack 3-6 phases (~1900+ cyc >> 900 HBM latency).
// WAR: every stage targets a slot whose last read was >=1 phase earlier,
//   sealed by an intervening barrier (checked per-phase).
// Prologue: 7 halves [k0 x4, k1 A0,B0,B1], VMW(6) retires k0, barrier.
// Tail: peeled last iter (kt=62): only ph1 stage (A1(63)); VMW(0) at ph4.

#define M_DIM 8192
#define N_DIM 4096
#define K_DIM 4096
#define BM 256
#define BN 256
#define BK 64
#define NKT (K_DIM / BK)   // 64 K-steps, 32 iters

typedef _Float16 f16;
typedef f16 f16x8 __attribute__((ext_vector_type(8)));
typedef f16 f16x2 __attribute__((ext_vector_type(2)));
typedef float f32x4 __attribute__((ext_vector_type(4)));

static __device__ __forceinline__ f16x2 cvt2(float a, float b) {
  return __builtin_bit_cast(f16x2, __builtin_amdgcn_cvt_pkrtz(a, b));
}

// ---------------- pre-pass kernels ----------------

__global__ __launch_bounds__(256) void conv_a_kernel(
    const float* __restrict__ A, f16* __restrict__ Af)
{
  const size_t stride = (size_t)gridDim.x * blockDim.x;
  size_t i = (size_t)blockIdx.x * blockDim.x + threadIdx.x;
  const size_t n8 = (size_t)M_DIM * K_DIM / 8;
  for (; i < n8; i += stride) {
    const f32x4* p = (const f32x4*)(A + i * 8);
    f32x4 v0 = p[0], v1 = p[1];
    f16x2 a = cvt2(v0.x, v0.y), b = cvt2(v0.z, v0.w);
    f16x2 c = cvt2(v1.x, v1.y), d = cvt2(v1.z, v1.w);
    *(f16x8*)(Af + i * 8) = (f16x8){a.x, a.y, b.x, b.y, c.x, c.y, d.x, d.y};
  }
}

__global__ __launch_bounds__(256) void conv_b_kernel(
    const int* __restrict__ Qw, const float* __restrict__ Sc,
    f16* __restrict__ Wf)
{
  const int o = blockIdx.x;
  const int t = threadIdx.x;
  const float s = Sc[o];
  const int* q = Qw + (size_t)o * K_DIM + t * 16;
  f16* w = Wf + (size_t)o * K_DIM + t * 16;
  #pragma unroll
  for (int h = 0; h < 2; ++h) {
    int4 u0 = *(const int4*)(q + h * 8);
    int4 u1 = *(const int4*)(q + h * 8 + 4);
    f16x2 a = cvt2((float)u0.x * s, (float)u0.y * s);
    f16x2 b = cvt2((float)u0.z * s, (float)u0.w * s);
    f16x2 c = cvt2((float)u1.x * s, (float)u1.y * s);
    f16x2 d = cvt2((float)u1.z * s, (float)u1.w * s);
    *(f16x8*)(w + h * 8) = (f16x8){a.x, a.y, b.x, b.y, c.x, c.y, d.x, d.y};
  }
}

// ---------------- main GEMM ----------------

#define BARX() __builtin_amdgcn_s_barrier()
#define SCHED0() __builtin_amdgcn_sched_barrier(0)
#define LGKM0() do { asm volatile("s_waitcnt lgkmcnt(0)" ::: "memory"); \
                     __builtin_amdgcn_sched_barrier(0); } while (0)
#define LGKM8() asm volatile("s_waitcnt lgkmcnt(8)" ::: "memory")
#define VMW(n) asm volatile("s_waitcnt vmcnt(" #n ")" ::: "memory")

// A-half qm: 8 ds_read_b128 -> af[j][ks]   (R5/R6 HW-verified layout)
#define LOADA(buf, qm) do { \
  const char* _b = (const char*)&As[buf][qm][0]; \
  _Pragma("unroll") \
  for (int j = 0; j < 4; ++j) { \
    const int _lr = (2 * j + wm) * 16 + fr; \
    af[j][0] = *(const f16x8*)(_b + _lr * 128 + (((qk    ) ^ x7) << 4)); \
    af[j][1] = *(const f16x8*)(_b + _lr * 128 + (((qk + 4) ^ x7) << 4)); \
  } } while (0)

// B-half qn: 4 ds_read_b128 -> bf[nl][ks]
#define LOADB(buf, qn, bf) do { \
  const char* _b = (const char*)&Bs[buf][qn][0]; \
  _Pragma("unroll") \
  for (int nl = 0; nl < 2; ++nl) { \
    const int _lr = nl * 64 + wn * 16 + fr; \
    bf[nl][0] = *(const f16x8*)(_b + _lr * 128 + (((qk    ) ^ x7) << 4)); \
    bf[nl][1] = *(const f16x8*)(_b + _lr * 128 + (((qk + 4) ^ x7) << 4)); \
  } } while (0)

// 16 MFMA for quadrant (qm, qn)
#define MFMAQ(qm, qn, bf) do { \
  __builtin_amdgcn_s_setprio(1); \
  _Pragma("unroll") \
  for (int j = 0; j < 4; ++j) \
    _Pragma("unroll") \
    for (int nl = 0; nl < 2; ++nl) { \
      acc[(qm)*4 + j][(qn)*2 + nl] = __builtin_amdgcn_mfma_f32_16x16x32_f16( \
          af[j][0], bf[nl][0], acc[(qm)*4 + j][(qn)*2 + nl], 0, 0, 0); \
      acc[(qm)*4 + j][(qn)*2 + nl] = __builtin_amdgcn_mfma_f32_16x16x32_f16( \
          af[j][1], bf[nl][1], acc[(qm)*4 + j][(qn)*2 + nl], 0, 0, 0); \
    } \
  __builtin_amdgcn_s_setprio(0); } while (0)

// stage one 128x64 f16 half-tile: 2 x global_load_lds(16B), linear LDS dest,
// inverse-swizzled global source (slot^(row&7))
#define STAGE(dstHalf, srcPanel, h, ktn) do { \
  _Pragma("unroll") \
  for (int _i = 0; _i < 2; ++_i) { \
    const f16* _g = (srcPanel) + (size_t)((h) * 128 + _i * 64 + st_row) * K_DIM \
                    + (ktn) * 64 + st_slot * 8; \
    char* _l = (char*)(dstHalf) + _i * 8192 + wid * 1024; \
    __builtin_amdgcn_global_load_lds( \
        (const __attribute__((address_space(1))) void*)_g, \
        (__attribute__((address_space(3))) void*)_l, 16, 0, 0); \
  } } while (0)

__global__ __launch_bounds__(512, 1) void w8a16_gemm_f16_kernel(
    const f16* __restrict__ Af,   // [M][K]
    const f16* __restrict__ Wf,   // [N][K], scale folded
    float* __restrict__ Out)      // [M][N]
{
  __shared__ __align__(16) f16 As[2][2][128 * 64];
  __shared__ __align__(16) f16 Bs[2][2][128 * 64];

  const int t    = threadIdx.x;
  const int lane = t & 63;
  const int wid  = t >> 6;       // 0..7
  const int wm   = wid >> 2;     // 0..1
  const int wn   = wid & 3;      // 0..3
  const int fr   = lane & 15;
  const int qk   = lane >> 4;
  const int x7   = fr & 7;

  const int st_row  = t >> 3;
  const int st_slot = (t & 7) ^ ((t >> 3) & 7);

  // XCD swizzle: 512 blocks, %8==0 -> simple bijective form
  const int bid = blockIdx.x;
  const int swz = (bid & 7) * 64 + (bid >> 3);
  const int tn  = swz & 15;      // 16 N-tiles
  const int tm  = swz >> 4;      // 32 M-tiles

  const f16* aSrc = Af + (size_t)tm * BM * K_DIM;
  const f16* bSrc = Wf + (size_t)tn * BN * K_DIM;

  f32x4 acc[8][4] = {};
  f16x8 af[4][2], bf0[2][2], bf1[2][2];

  // prologue: 7 halves in FIFO order; VMW(6) retires all of k0
  STAGE(&As[0][0][0], aSrc, 0, 0);   // A0(k0)
  STAGE(&Bs[0][0][0], bSrc, 0, 0);   // B0(k0)
  STAGE(&Bs[0][1][0], bSrc, 1, 0);   // B1(k0)
  STAGE(&As[0][1][0], aSrc, 1, 0);   // A1(k0)
  STAGE(&As[1][0][0], aSrc, 0, 1);   // A0(k1)
  STAGE(&Bs[1][0][0], bSrc, 0, 1);   // B0(k1)
  STAGE(&Bs[1][1][0], bSrc, 1, 1);   // B1(k1)
  VMW(6);
  BARX();
  SCHED0();

  // 31 full iters (kt = 0..60), branch-free
  for (int kt = 0; kt < NKT - 2; kt += 2) {
    // ph1: q(0,0) on buf0; stage buf1.A1(kt+1)
    LOADA(0, 0);
    LOADB(0, 0, bf0);
    STAGE(&As[1][1][0], aSrc, 1, kt + 1);
    LGKM8();
    BARX(); LGKM0();
    MFMAQ(0, 0, bf0);
    BARX();
    // ph2: q(0,1); stage buf0.A0(kt+2)
    LOADB(0, 1, bf1);
    STAGE(&As[0][0][0], aSrc, 0, kt + 2);
    BARX(); LGKM0();
    MFMAQ(0, 1, bf1);
    BARX();
    // ph3: q(1,1); stage buf0.B0(kt+2)
    LOADA(0, 1);
    STAGE(&Bs[0][0][0], bSrc, 0, kt + 2);
    BARX(); LGKM0();
    MFMAQ(1, 1, bf1);
    BARX();
    // ph4: q(1,0); stage buf0.B1(kt+2); counted seal -> kt+1 confirmed
    STAGE(&Bs[0][1][0], bSrc, 1, kt + 2);
    VMW(6);
    BARX();
    MFMAQ(1, 0, bf0);
    BARX();
    // ph5: q(0,0) on buf1 (kt+1); stage buf0.A1(kt+2)
    LOADA(1, 0);
    LOADB(1, 0, bf0);
    STAGE(&As[0][1][0], aSrc, 1, kt + 2);
    LGKM8();
    BARX(); LGKM0();
    MFMAQ(0, 0, bf0);
    BARX();
    // ph6: q(0,1); stage buf1.A0(kt+3)
    LOADB(1, 1, bf1);
    STAGE(&As[1][0][0], aSrc, 0, kt + 3);
    BARX(); LGKM0();
    MFMAQ(0, 1, bf1);
    BARX();
    // ph7: q(1,1); stage buf1.B0(kt+3)
    LOADA(1, 1);
    STAGE(&Bs[1][0][0], bSrc, 0, kt + 3);
    BARX(); LGKM0();
    MFMAQ(1, 1, bf1);
    BARX();
    // ph8: q(1,0); stage buf1.B1(kt+3); counted seal -> kt+2 confirmed
    STAGE(&Bs[1][1][0], bSrc, 1, kt + 3);
    VMW(6);
    BARX();
    MFMAQ(1, 0, bf0);
    BARX();
  }

  { // peeled last iter: kt = 62,63; only ph1 stages (A1(63)); VMW(0) @ph4
    LOADA(0, 0);
    LOADB(0, 0, bf0);
    STAGE(&As[1][1][0], aSrc, 1, NKT - 1);
    LGKM8();
    BARX(); LGKM0();
    MFMAQ(0, 0, bf0);
    BARX();

    LOADB(0, 1, bf1);
    BARX(); LGKM0();
    MFMAQ(0, 1, bf1);
    BARX();

    LOADA(0, 1);
    BARX(); LGKM0();
    MFMAQ(1, 1, bf1);
    BARX();

    VMW(0);
    BARX();
    MFMAQ(1, 0, bf0);
    BARX();

    LOADA(1, 0);
    LOADB(1, 0, bf0);
    BARX(); LGKM0();
    MFMAQ(0, 0, bf0);
    BARX();

    LOADB(1, 1, bf1);
    BARX(); LGKM0();
    MFMAQ(0, 1, bf1);
    BARX();

    LOADA(1, 1);
    BARX(); LGKM0();
    MFMAQ(1, 1, bf1);
    BARX();

    MFMAQ(1, 0, bf0);
  }

  // epilogue: C/D col = lane&15, row = (lane>>4)*4 + reg
  const int fq = lane >> 4;
  #pragma unroll
  for (int mi = 0; mi < 8; ++mi) {
    const size_t row = (size_t)tm * BM + (mi * 2 + wm) * 16 + fq * 4;
    #pragma unroll
    for (int ni = 0; ni < 4; ++ni) {
      const size_t col = (size_t)tn * BN + ni * 64 + wn * 16 + fr;
      #pragma unroll
      for (int r = 0; r < 4; ++r)
        Out[(row + r) * N_DIM + col] = acc[mi][ni][r];
    }
  }
}

// ---------------- fallback (round-3 verified path) ----------------

__global__ __launch_bounds__(256) void w8a16_gemm_fb_kernel(
    const float* __restrict__ A, const int* __restrict__ Qw,
    const float* __restrict__ Sc, float* __restrict__ Out)
{
  __shared__ __align__(16) float Asf[2][128 * 32];
  __shared__ __align__(16) f16 Bsf[2][128][32];

  const int t = threadIdx.x, lane = t & 63, wid = t >> 6;
  const int wr = wid >> 1, wc = wid & 1;
  const int nwg = gridDim.x, cpx = nwg >> 3, bid = blockIdx.x;
  const int swz = (bid & 7) * cpx + (bid >> 3);
  const int tn = swz & 31, tm = swz >> 5;
  const size_t a_base = (size_t)tm * 128 * K_DIM;
  const size_t b_base = (size_t)tn * 128 * K_DIM;
  f32x4 acc[4][4] = {};
  const int a_r = t >> 3;
  const int a_slog = (t & 7) ^ ((t >> 3) & 7);

  auto stageA = [&](int buf, int kt) {
    #pragma unroll
    for (int c = 0; c < 4; ++c) {
      const float* g = A + a_base + (size_t)(c * 32 + a_r) * K_DIM + kt * 32 + a_slog * 4;
      char* l = (char*)&Asf[buf][0] + c * 4096 + wid * 1024;
      __builtin_amdgcn_global_load_lds(
          (const __attribute__((address_space(1))) void*)g,
          (__attribute__((address_space(3))) void*)l, 16, 0, 0);
    }
  };
  const int b_r = t >> 3, b_col = (t & 7) * 4;
  auto loadB = [&](int kt, int4* v) {
    #pragma unroll
    for (int c = 0; c < 4; ++c)
      v[c] = *(const int4*)(Qw + b_base + (size_t)(c * 32 + b_r) * K_DIM + kt * 32 + b_col);
  };
  auto writeB = [&](int buf, const int4* v) {
    #pragma unroll
    for (int c = 0; c < 4; ++c) {
      f16x2 lo = cvt2((float)v[c].x, (float)v[c].y);
      f16x2 hi = cvt2((float)v[c].z, (float)v[c].w);
      *(f16x2*)&Bsf[buf][c * 32 + b_r][b_col] = lo;
      *(f16x2*)&Bsf[buf][c * 32 + b_r][b_col + 2] = hi;
    }
  };
  auto compute = [&](int buf) {
    const int fr2 = lane & 15, q = lane >> 4;
    f16x8 af2[4], bf2[4];
    #pragma unroll
    for (int i = 0; i < 4; ++i) {
      const int r = wr * 64 + i * 16 + fr2;
      const float* base = &Asf[buf][0] + r * 32;
      const int s0 = q * 2;
      f32x4 a0 = *(const f32x4*)(base + ((s0 ^ (r & 7)) * 4));
      f32x4 a1 = *(const f32x4*)(base + (((s0 + 1) ^ (r & 7)) * 4));
      f16x2 p0 = cvt2(a0.x, a0.y), p1 = cvt2(a0.z, a0.w);
      f16x2 p2 = cvt2(a1.x, a1.y), p3 = cvt2(a1.z, a1.w);
      af2[i] = (f16x8){p0.x, p0.y, p1.x, p1.y, p2.x, p2.y, p3.x, p3.y};
      bf2[i] = *(const f16x8*)&Bsf[buf][wc * 64 + i * 16 + fr2][q * 8];
    }
    #pragma unroll
    for (int mi = 0; mi < 4; ++mi)
      #pragma unroll
      for (int ni = 0; ni < 4; ++ni)
        acc[mi][ni] = __builtin_amdgcn_mfma_f32_16x16x32_f16(
            af2[mi], bf2[ni], acc[mi][ni], 0, 0, 0);
  };

  { int4 b0[4]; stageA(0, 0); loadB(0, b0); writeB(0, b0); }
  __syncthreads();
  for (int kt = 0; kt < K_DIM / 32; ++kt) {
    const int buf = kt & 1;
    const bool more = (kt + 1) < K_DIM / 32;
    int4 nb[4];
    if (more) { stageA(buf ^ 1, kt + 1); loadB(kt + 1, nb); }
    compute(buf);
    if (more) writeB(buf ^ 1, nb);
    __syncthreads();
  }
  const int fr2 = lane & 15, fq = lane >> 4;
  const int cb = tn * 128 + wc * 64 + fr2;
  const int rb = tm * 128 + wr * 64 + fq * 4;
  #pragma unroll
  for (int ni = 0; ni < 4; ++ni) {
    const float s = Sc[cb + ni * 16];
    #pragma unroll
    for (int mi = 0; mi < 4; ++mi)
      #pragma unroll
      for (int r = 0; r < 4; ++r)
        Out[(size_t)(rb + mi * 16 + r) * N_DIM + (cb + ni * 16)] =
            acc[mi][ni][r] * s;
  }
}

extern "C" void kernel_launch(void* const* d_in, const int* in_sizes, int n_in,
                              void* d_out, int out_size, void* d_ws, size_t ws_size,
                              hipStream_t stream) {
  const float* A  = (const float*)d_in[0];
  const int*   Qw = (const int*)d_in[1];
  const float* Sc = (const float*)d_in[2];
  float*       Out = (float*)d_out;

  const size_t a_bytes = (size_t)M_DIM * K_DIM * sizeof(f16);  // 64 MB
  const size_t w_bytes = (size_t)N_DIM * K_DIM * sizeof(f16);  // 32 MB

  if (ws_size >= a_bytes + w_bytes) {
    f16* Af = (f16*)d_ws;
    f16* Wf = (f16*)((char*)d_ws + a_bytes);
    conv_a_kernel<<<2048, 256, 0, stream>>>(A, Af);
    conv_b_kernel<<<N_DIM, 256, 0, stream>>>(Qw, Sc, Wf);
    dim3 grid((M_DIM / BM) * (N_DIM / BN));  // 32*16 = 512
    w8a16_gemm_f16_kernel<<<grid, 512, 0, stream>>>(Af, Wf, Out);
  } else {
    dim3 grid((M_DIM / 128) * (N_DIM / 128));
    w8a16_gemm_fb_kernel<<<grid, 256, 0, stream>>>(A, Qw, Sc, Out);
  }
}